// Round 7
// baseline (166.140 us; speedup 1.0000x reference)
//
#include <hip/hip_runtime.h>

// Problem constants
#define BQ 4
#define SQ 4096
#define HIDN 768
#define NH 12
#define DH 64
#define BH (BQ * NH)          // 48
#define WIN 128
#define MROWS (BQ * SQ)       // 16384
#define NCOLS (3 * HIDN)      // 2304
#define KDIM HIDN             // 768
#define BHD_ELEMS (BH * SQ * DH)   // 12582912

using bfrag  = __attribute__((ext_vector_type(8))) short;    // 8 bf16 (4 VGPRs)
using f32x4  = __attribute__((ext_vector_type(4))) float;
using f32x16 = __attribute__((ext_vector_type(16))) float;
using us8    = __attribute__((ext_vector_type(8))) unsigned short;

__device__ __forceinline__ unsigned short f2bf(float f) {
  union { float f; unsigned u; } x; x.f = f;
  unsigned r = x.u + 0x7fffu + ((x.u >> 16) & 1u);   // RNE
  return (unsigned short)(r >> 16);
}
__device__ __forceinline__ unsigned f2bf2(float lo, float hi) {
  return (unsigned)f2bf(lo) | ((unsigned)f2bf(hi) << 16);
}
__device__ __forceinline__ unsigned cvtpk(float lo, float hi) {
  unsigned u;
  asm("v_cvt_pk_bf16_f32 %0, %1, %2" : "=v"(u) : "v"(lo), "v"(hi));
  return u;
}

__device__ __forceinline__ void gload16(const void* g, void* l) {
  __builtin_amdgcn_global_load_lds(
      (const __attribute__((address_space(1))) unsigned int*)g,
      (__attribute__((address_space(3))) unsigned int*)l, 16, 0, 0);
}

// ---------------- kernel 0: convert Wq|Wk|Wv fp32 -> bf16 [2304][768] ----------------
__global__ __launch_bounds__(256) void wconv_kernel(
    const float* __restrict__ Wq, const float* __restrict__ Wk,
    const float* __restrict__ Wv, unsigned short* __restrict__ wb)
{
  int g = (blockIdx.x * 256 + threadIdx.x) * 4;
  if (g >= NCOLS * KDIM) return;
  int n = g / KDIM, k = g - n * KDIM;
  int wsel = n / HIDN, nl = n - wsel * HIDN;
  const float* W = (wsel == 0) ? Wq : (wsel == 1) ? Wk : Wv;
  float4 v = *reinterpret_cast<const float4*>(&W[nl * KDIM + k]);
  ushort4 p;
  p.x = f2bf(v.x); p.y = f2bf(v.y); p.z = f2bf(v.z); p.w = f2bf(v.w);
  *reinterpret_cast<ushort4*>(&wb[g]) = p;
}

// ---------------- kernel 1: fused QKV projection (bf16 MFMA) ----------------
// A staged as RAW FP32 from hidden (no pre-conversion pass): [128][64] f32 LDS,
// granule swizzle g^=((row&7)<<1) (inverse-swizzled global src, linear gload_lds dest),
// in-register cvt_pk -> bf16 at fragment read. B stays bf16 with proven swizzle.
#define BM 128
#define BN 128
#define BKK 64

__global__ __launch_bounds__(256) void proj_kernel(
    const float* __restrict__ hid,
    const unsigned short* __restrict__ wb,
    const float* __restrict__ bq, const float* __restrict__ bk,
    const float* __restrict__ bv,
    unsigned short* __restrict__ qb, unsigned short* __restrict__ kb,
    unsigned short* __restrict__ vb)
{
  __shared__ float          Asf[BM][BKK];   // 32 KB fp32 A tile
  __shared__ unsigned short Bs[BN][BKK];    // 16 KB bf16 B tile

  const int t = threadIdx.x;
  // XCD-bijective swizzle: 2304 blocks, 2304%8==0 -> chunk 288 per XCD
  const int id = blockIdx.x;
  const int swz = (id & 7) * (NCOLS * MROWS / (BM * BN) / 8) + (id >> 3);
  const int bx = swz % (NCOLS / BN);    // 18 N-tiles (A-panel L2 reuse within XCD)
  const int by = swz / (NCOLS / BN);    // 128 M-tiles
  const int m0 = by * BM;
  const int n0 = bx * BN;
  const int wsel = bx / 6;              // 0=q 1=k 2=v (each 6 N-tiles)
  const float* bias = (wsel == 0) ? bq : (wsel == 1) ? bk : bv;
  const int nloc0 = n0 - wsel * HIDN;

  const int lane = t & 63;
  const int w = t >> 6;
  const int wm = w >> 1, wn = w & 1;
  const int fr = lane & 15, fq = lane >> 4;
  const int xsw = (fr & 7) << 3;        // B read-side XOR (bf16 elem units)
  const int xg  = (fr & 7) << 1;        // A read-side XOR (16B granule units)

  // ---- A staging (fp32): 8 insts/iter; inst i covers rows w*32+i*4+(l>>4) ----
  // lane granule ga=l&15; source granule = ga ^ ((i&1)<<3) ^ (s0<<1); LDS dest linear
  const int s0 = lane >> 4;
  const int ga = lane & 15;
  const float* gA0 = &hid[(size_t)(m0 + w * 32 + s0) * KDIM + ((ga ^ (s0 << 1)) << 2)];
  const float* gA1 = &hid[(size_t)(m0 + w * 32 + s0) * KDIM + (((ga ^ 8) ^ (s0 << 1)) << 2)];

  // ---- B staging (bf16): 4 insts/iter; inst i covers 8 rows ----
  const int srow = w * 32 + (lane >> 3);
  const int scol = ((lane & 7) * 8) ^ ((lane >> 3) << 3);
  const unsigned short* gB = &wb[(size_t)(n0 + srow) * KDIM + scol];

  f32x4 acc[4][4] = {};

  for (int kt = 0; kt < KDIM / BKK; ++kt) {
    const int k0 = kt * BKK;
    __syncthreads();                                 // prev compute's ds_reads done
    #pragma unroll
    for (int i = 0; i < 8; ++i) {
      const float* src = ((i & 1) ? gA1 : gA0) + (size_t)(i * 4) * KDIM + k0;
      gload16(src, &Asf[w * 32 + i * 4][0]);
    }
    #pragma unroll
    for (int i = 0; i < 4; ++i)
      gload16(gB + k0 + (size_t)(i * 8) * KDIM, &Bs[w * 32 + i * 8][0]);
    __syncthreads();                                 // loads landed
    #pragma unroll
    for (int kk = 0; kk < 2; ++kk) {
      bfrag a[4], b[4];
      #pragma unroll
      for (int i = 0; i < 4; ++i) {
        const float* rowp = &Asf[wm * 64 + i * 16 + fr][0];
        const int g0 = (kk * 8 + fq * 2) ^ xg;       // even ^ even -> even
        f32x4 lo = *reinterpret_cast<const f32x4*>(rowp + g0 * 4);
        f32x4 hi = *reinterpret_cast<const f32x4*>(rowp + g0 * 4 + 4);
        uint4 ua;
        ua.x = cvtpk(lo[0], lo[1]); ua.y = cvtpk(lo[2], lo[3]);
        ua.z = cvtpk(hi[0], hi[1]); ua.w = cvtpk(hi[2], hi[3]);
        a[i] = *reinterpret_cast<bfrag*>(&ua);
      }
      #pragma unroll
      for (int j = 0; j < 4; ++j)
        b[j] = *reinterpret_cast<const bfrag*>(&Bs[wn * 64 + j * 16 + fr][(kk * 32 + fq * 8) ^ xsw]);
      #pragma unroll
      for (int i = 0; i < 4; ++i)
        #pragma unroll
        for (int j = 0; j < 4; ++j)
          acc[i][j] = __builtin_amdgcn_mfma_f32_16x16x32_bf16(b[j], a[i], acc[i][j], 0, 0, 0);
    }
  }

  // epilogue: D-row <-> n (4 consecutive per lane), D-col <-> m. 8B stores.
  unsigned short* outb = (wsel == 0) ? qb : (wsel == 1) ? kb : vb;
  // fold 1/sqrt(64) AND log2(e) into q so attention scores are in exp2 domain
  const float qscale = (wsel == 0) ? 0.125f * 1.44269504088896f : 1.0f;
  const int b_ = m0 >> 12;
  #pragma unroll
  for (int j = 0; j < 4; ++j) {
    int nl = nloc0 + wn * 64 + j * 16 + fq * 4;        // 4 consecutive n
    int h = nl >> 6, d0 = nl & 63;
    float4 bs4 = *reinterpret_cast<const float4*>(&bias[nl]);
    unsigned short* obase = outb + (size_t)(b_ * NH + h) * SQ * DH + d0;
    #pragma unroll
    for (int i = 0; i < 4; ++i) {
      int m = m0 + wm * 64 + i * 16 + fr;              // D-col = lane&15
      int srow_ = m & (SQ - 1);
      f32x4 v = acc[i][j];
      uint2 pk;
      pk.x = f2bf2((v[0] + bs4.x) * qscale, (v[1] + bs4.y) * qscale);
      pk.y = f2bf2((v[2] + bs4.z) * qscale, (v[3] + bs4.w) * qscale);
      *reinterpret_cast<uint2*>(&obase[(size_t)srow_ * DH]) = pk;
    }
  }
}

// ---------------- kernel 2: sliding-window flash attention (32x32 MFMA) ----------------
// 1D grid 1536, XCD-bijective swizzle (each XCD: contiguous chunks of one head ->
// K/V window overlap is an L2 hit). 4 waves x 32 queries; swapped QK^T; online
// softmax (defer-max, exp2); P->A-frag via cvt_pk + shfl_xor(32); K-frag prefetch.
#define VLD 392          // 384 keys + 8 pad (stride 196 dwords -> b128 at conflict floor)
#define THR 11.6f        // defer-max threshold (8 nats in log2 units)

__global__ __launch_bounds__(256, 3) void attn_kernel(
    const unsigned short* __restrict__ qb,
    const unsigned short* __restrict__ kb,
    const unsigned short* __restrict__ vb,
    float* __restrict__ out)
{
  __shared__ unsigned short Vt[DH][VLD];     // V^T for this block's 384-key range

  const int id = blockIdx.x;                 // 1536 blocks, 1536%8==0
  const int swz = (id & 7) * (BH * SQ / 128 / 8) + (id >> 3);
  const int c = swz & 31;                    // query chunk (fast within XCD range)
  const int bh = swz >> 5;                   // head
  const int t = threadIdx.x;
  const int lane = t & 63;
  const int w = t >> 6;
  const int b_ = bh / NH, hd = bh - b_ * NH;
  const int qi = lane & 31, h = lane >> 5;

  const unsigned short* Qbh = qb + bh * (SQ * DH);
  const unsigned short* Kbh = kb + bh * (SQ * DH);
  const unsigned short* Vbh = vb + bh * (SQ * DH);

  const int kstart = c * 128 - WIN;          // block key range [kstart, kstart+384)

  // ---- stage V^T: item = (kg 0..47 [8 keys], dg 0..15 [4 d]); 16B LDS writes ----
  for (int it = t; it < 48 * 16; it += 256) {
    int dg = it & 15, kg = it >> 4;
    int kr = kstart + kg * 8;
    ushort4 va[8];
    #pragma unroll
    for (int rr = 0; rr < 8; ++rr) {
      int k = kr + rr;
      int kc = k < 0 ? 0 : (k > SQ - 1 ? SQ - 1 : k);
      va[rr] = *reinterpret_cast<const ushort4*>(&Vbh[(size_t)kc * DH + dg * 4]);
    }
    #pragma unroll
    for (int j = 0; j < 4; ++j) {
      us8 row;
      #pragma unroll
      for (int i = 0; i < 8; ++i)
        row[i] = reinterpret_cast<const unsigned short*>(&va[i])[j];
      *reinterpret_cast<us8*>(&Vt[dg * 4 + j][kg * 8]) = row;
    }
  }
  __syncthreads();

  // ---- per-wave setup ----
  const int q0w = c * 128 + w * 32;
  const int q = q0w + qi;
  const int kw = q0w - WIN;
  bfrag qf[4];
  #pragma unroll
  for (int kk = 0; kk < 4; ++kk)
    qf[kk] = *reinterpret_cast<const bfrag*>(&Qbh[(size_t)q * DH + kk * 16 + h * 8]);

  const int lo = (-q > -WIN) ? -q : -WIN;
  const int hi = (SQ - 1 - q < WIN) ? (SQ - 1 - q) : WIN;
  const int hq = 4 * h - qi;
  const bool edge = (c == 0) || (c == 31);

  f32x16 c0 = {}, c1 = {};
  float m = -3e38f, ls = 0.f;

  // prefetch K tile 0
  bfrag kf[4];
  {
    int krow = kw + qi;
    int kc = krow < 0 ? 0 : (krow > SQ - 1 ? SQ - 1 : krow);
    #pragma unroll
    for (int kk = 0; kk < 4; ++kk)
      kf[kk] = *reinterpret_cast<const bfrag*>(&Kbh[(size_t)kc * DH + kk * 16 + h * 8]);
  }

  for (int kt = 0; kt < 9; ++kt) {
    // issue K loads for tile kt+1 (overlaps with this tile's compute)
    bfrag kfn[4];
    if (kt < 8) {
      int krow = kw + (kt + 1) * 32 + qi;
      int kc = krow < 0 ? 0 : (krow > SQ - 1 ? SQ - 1 : krow);
      #pragma unroll
      for (int kk = 0; kk < 4; ++kk)
        kfn[kk] = *reinterpret_cast<const bfrag*>(&Kbh[(size_t)kc * DH + kk * 16 + h * 8]);
    }

    f32x16 D = {};
    __builtin_amdgcn_s_setprio(1);
    #pragma unroll
    for (int kk = 0; kk < 4; ++kk)
      D = __builtin_amdgcn_mfma_f32_32x32x16_bf16(kf[kk], qf[kk], D, 0, 0, 0);
    __builtin_amdgcn_s_setprio(0);

    // mask (only boundary tiles / edge blocks need it)
    if (edge || kt == 0 || kt == 8) {
      #pragma unroll
      for (int r = 0; r < 16; ++r) {
        int klocal = (r & 3) + 8 * (r >> 2);
        int dk = kt * 32 + klocal - WIN + hq;
        if (dk < lo || dk > hi) D[r] = -1e30f;
      }
    }

    // tile max (per q column)
    float pm = D[0];
    #pragma unroll
    for (int r = 1; r < 16; ++r) pm = fmaxf(pm, D[r]);
    pm = fmaxf(pm, __shfl_xor(pm, 32));

    // defer-max online rescale
    if (!__all(pm <= m + THR)) {
      float mn = fmaxf(m, pm);
      float al = __builtin_amdgcn_exp2f(m - mn);
      #pragma unroll
      for (int r = 0; r < 16; ++r) {
        float av = __shfl(al, (r & 3) + 8 * (r >> 2) + 4 * h);
        c0[r] *= av; c1[r] *= av;
      }
      ls *= al;
      m = mn;
    }

    // P = exp2(D - m); row-sum partials
    float p[16];
    float sum = 0.f;
    #pragma unroll
    for (int r = 0; r < 16; ++r) {
      p[r] = __builtin_amdgcn_exp2f(D[r] - m);
      sum += p[r];
    }
    ls += sum;

    // convert to bf16 pairs, exchange halves -> PV A-frags
    unsigned U[8];
    #pragma unroll
    for (int g = 0; g < 8; ++g) U[g] = cvtpk(p[2 * g], p[2 * g + 1]);

    unsigned f0[4], f1[4];
    {
      unsigned x, y, xs, ys;
      x = U[0]; y = U[2]; xs = __shfl_xor(x, 32); ys = __shfl_xor(y, 32);
      f0[0] = h ? ys : x;  f0[2] = h ? y : xs;
      x = U[1]; y = U[3]; xs = __shfl_xor(x, 32); ys = __shfl_xor(y, 32);
      f0[1] = h ? ys : x;  f0[3] = h ? y : xs;
      x = U[4]; y = U[6]; xs = __shfl_xor(x, 32); ys = __shfl_xor(y, 32);
      f1[0] = h ? ys : x;  f1[2] = h ? y : xs;
      x = U[5]; y = U[7]; xs = __shfl_xor(x, 32); ys = __shfl_xor(y, 32);
      f1[1] = h ? ys : x;  f1[3] = h ? y : xs;
    }

    // PV: 2 k-steps x 2 d-tiles
    const int colbase = w * 32 + kt * 32;
    bfrag paA, paB;
    {
      uint4 ua = {f0[0], f0[1], f0[2], f0[3]};
      uint4 ub = {f1[0], f1[1], f1[2], f1[3]};
      paA = *reinterpret_cast<bfrag*>(&ua);
      paB = *reinterpret_cast<bfrag*>(&ub);
    }
    bfrag v00 = *reinterpret_cast<const bfrag*>(&Vt[qi][colbase + h * 8]);
    bfrag v01 = *reinterpret_cast<const bfrag*>(&Vt[32 + qi][colbase + h * 8]);
    bfrag v10 = *reinterpret_cast<const bfrag*>(&Vt[qi][colbase + 16 + h * 8]);
    bfrag v11 = *reinterpret_cast<const bfrag*>(&Vt[32 + qi][colbase + 16 + h * 8]);
    __builtin_amdgcn_s_setprio(1);
    c0 = __builtin_amdgcn_mfma_f32_32x32x16_bf16(paA, v00, c0, 0, 0, 0);
    c1 = __builtin_amdgcn_mfma_f32_32x32x16_bf16(paA, v01, c1, 0, 0, 0);
    c0 = __builtin_amdgcn_mfma_f32_32x32x16_bf16(paB, v10, c0, 0, 0, 0);
    c1 = __builtin_amdgcn_mfma_f32_32x32x16_bf16(paB, v11, c1, 0, 0, 0);
    __builtin_amdgcn_s_setprio(0);

    #pragma unroll
    for (int kk = 0; kk < 4; ++kk) kf[kk] = kfn[kk];
  }

  // ---- epilogue: combine l across halves, normalize, write ----
  float lt = ls + __shfl_xor(ls, 32);
  float rinv = 1.0f / lt;
  #pragma unroll
  for (int r = 0; r < 16; ++r) {
    int qrow = (r & 3) + 8 * (r >> 2) + 4 * h;
    float rv = __shfl(rinv, qrow);
    size_t obase = (size_t)(b_ * SQ + q0w + qrow) * HIDN + hd * DH;
    out[obase + qi] = c0[r] * rv;
    out[obase + 32 + qi] = c1[r] * rv;
  }
}

extern "C" void kernel_launch(void* const* d_in, const int* in_sizes, int n_in,
                              void* d_out, int out_size, void* d_ws, size_t ws_size,
                              hipStream_t stream) {
  const float* hid = (const float*)d_in[0];
  const float* Wq  = (const float*)d_in[1];
  const float* bq  = (const float*)d_in[2];
  const float* Wk  = (const float*)d_in[3];
  const float* bk  = (const float*)d_in[4];
  const float* Wv  = (const float*)d_in[5];
  const float* bv  = (const float*)d_in[6];
  float* out = (float*)d_out;

  // ws layout: qb | kb | vb (bf16 [48][4096][64] each) | wb bf16 [2304][768]
  unsigned short* qb = (unsigned short*)d_ws;
  unsigned short* kb = qb + BHD_ELEMS;
  unsigned short* vb = kb + BHD_ELEMS;
  unsigned short* wb = vb + BHD_ELEMS;

  int nconv = (NCOLS * KDIM / 4 + 255) / 256;
  wconv_kernel<<<dim3(nconv), dim3(256), 0, stream>>>(Wq, Wk, Wv, wb);

  dim3 g1(NCOLS * MROWS / (BM * BN));   // 2304, XCD-swizzled in-kernel
  proj_kernel<<<g1, dim3(256), 0, stream>>>(hid, wb, bq, bk, bv, qb, kb, vb);

  dim3 g2(BH * SQ / 128);               // 1536, XCD-swizzled in-kernel
  attn_kernel<<<g2, dim3(256), 0, stream>>>(qb, kb, vb, out);
}

// Round 8
// 143.005 us; speedup vs baseline: 1.1618x; 1.1618x over previous
//
#include <hip/hip_runtime.h>

// Problem constants
#define BQ 4
#define SQ 4096
#define HIDN 768
#define NH 12
#define DH 64
#define BH (BQ * NH)          // 48
#define WIN 128
#define MROWS (BQ * SQ)       // 16384
#define NCOLS (3 * HIDN)      // 2304
#define KDIM HIDN             // 768
#define BHD_ELEMS (BH * SQ * DH)   // 12582912

using bfrag  = __attribute__((ext_vector_type(8))) short;    // 8 bf16 (4 VGPRs)
using f32x4  = __attribute__((ext_vector_type(4))) float;
using f32x16 = __attribute__((ext_vector_type(16))) float;
using us8    = __attribute__((ext_vector_type(8))) unsigned short;

__device__ __forceinline__ unsigned short f2bf(float f) {
  union { float f; unsigned u; } x; x.f = f;
  unsigned r = x.u + 0x7fffu + ((x.u >> 16) & 1u);   // RNE
  return (unsigned short)(r >> 16);
}
__device__ __forceinline__ unsigned f2bf2(float lo, float hi) {
  return (unsigned)f2bf(lo) | ((unsigned)f2bf(hi) << 16);
}
__device__ __forceinline__ unsigned cvtpk(float lo, float hi) {
  unsigned u;
  asm("v_cvt_pk_bf16_f32 %0, %1, %2" : "=v"(u) : "v"(lo), "v"(hi));
  return u;
}

__device__ __forceinline__ void gload16(const void* g, void* l) {
  __builtin_amdgcn_global_load_lds(
      (const __attribute__((address_space(1))) unsigned int*)g,
      (__attribute__((address_space(3))) unsigned int*)l, 16, 0, 0);
}

// ---------------- kernel 0: convert W (blocks 0..1727) + hidden (rest) to bf16 ----------------
#define WBLK (NCOLS * KDIM / 4 / 256)   // 1728
#define HBLK 2048

__global__ __launch_bounds__(256) void conv_kernel(
    const float* __restrict__ hid,
    const float* __restrict__ Wq, const float* __restrict__ Wk,
    const float* __restrict__ Wv,
    unsigned short* __restrict__ wb, unsigned short* __restrict__ hb)
{
  const int bid = blockIdx.x;
  if (bid < WBLK) {
    int g = (bid * 256 + threadIdx.x) * 4;
    int n = g / KDIM, k = g - n * KDIM;
    int wsel = n / HIDN, nl = n - wsel * HIDN;
    const float* W = (wsel == 0) ? Wq : (wsel == 1) ? Wk : Wv;
    float4 v = *reinterpret_cast<const float4*>(&W[nl * KDIM + k]);
    ushort4 p;
    p.x = f2bf(v.x); p.y = f2bf(v.y); p.z = f2bf(v.z); p.w = f2bf(v.w);
    *reinterpret_cast<ushort4*>(&wb[g]) = p;
  } else {
    const int N8 = MROWS * KDIM / 8;
    for (int idx = (bid - WBLK) * 256 + threadIdx.x; idx < N8; idx += HBLK * 256) {
      const float4* src = reinterpret_cast<const float4*>(hid) + (size_t)idx * 2;
      float4 a = src[0], b = src[1];
      uint4 o;
      o.x = f2bf2(a.x, a.y); o.y = f2bf2(a.z, a.w);
      o.z = f2bf2(b.x, b.y); o.w = f2bf2(b.z, b.w);
      *reinterpret_cast<uint4*>(&hb[(size_t)idx * 8]) = o;
    }
  }
}

// ---------------- kernel 1: fused QKV projection (bf16 MFMA, R3/R5-proven structure) ----------------
// BK=64, T2 XOR-swizzled LDS (linear gload_lds dest + inverse-swizzled global src),
// swapped-operand MFMA so each lane holds 4 consecutive d -> 8B stores.
#define BM 128
#define BN 128
#define BKK 64

__global__ __launch_bounds__(256) void proj_kernel(
    const unsigned short* __restrict__ hb,
    const unsigned short* __restrict__ wb,
    const float* __restrict__ bq, const float* __restrict__ bk,
    const float* __restrict__ bv,
    unsigned short* __restrict__ qb, unsigned short* __restrict__ kb,
    unsigned short* __restrict__ vb)
{
  __shared__ unsigned short As[BM][BKK];
  __shared__ unsigned short Bs[BN][BKK];

  const int t = threadIdx.x;
  // XCD-bijective swizzle: 2304 blocks, 2304%8==0 -> chunk 288 per XCD
  const int id = blockIdx.x;
  const int swz = (id & 7) * (NCOLS * MROWS / (BM * BN) / 8) + (id >> 3);
  const int bx = swz % (NCOLS / BN);    // 18 N-tiles (A-panel L2 reuse within XCD)
  const int by = swz / (NCOLS / BN);    // 128 M-tiles
  const int m0 = by * BM;
  const int n0 = bx * BN;
  const int wsel = bx / 6;              // 0=q 1=k 2=v (each 6 N-tiles)
  const float* bias = (wsel == 0) ? bq : (wsel == 1) ? bk : bv;
  const int nloc0 = n0 - wsel * HIDN;

  const int lane = t & 63;
  const int w = t >> 6;
  const int wm = w >> 1, wn = w & 1;
  const int fr = lane & 15, fq = lane >> 4;
  const int xsw = (fr & 7) << 3;        // read-side XOR (elem units)

  // staging: wave w owns rows w*32..+31; inst i covers 8 rows (64 lanes x 16B = 1KB)
  // LDS dest linear; global src col inverse-swizzled: elem = ((l&7)*8) ^ ((l>>3)<<3)
  const int srow = w * 32 + (lane >> 3);
  const int scol = ((lane & 7) * 8) ^ ((lane >> 3) << 3);
  const unsigned short* gA = &hb[(size_t)(m0 + srow) * KDIM + scol];
  const unsigned short* gB = &wb[(size_t)(n0 + srow) * KDIM + scol];

  f32x4 acc[4][4] = {};

  for (int kt = 0; kt < KDIM / BKK; ++kt) {
    const int k0 = kt * BKK;
    __syncthreads();                                 // prev compute's ds_reads done
    #pragma unroll
    for (int i = 0; i < 4; ++i) {
      gload16(gA + k0 + (size_t)(i * 8) * KDIM, &As[w * 32 + i * 8][0]);
      gload16(gB + k0 + (size_t)(i * 8) * KDIM, &Bs[w * 32 + i * 8][0]);
    }
    __syncthreads();                                 // loads landed
    #pragma unroll
    for (int kk = 0; kk < 2; ++kk) {
      bfrag a[4], b[4];
      #pragma unroll
      for (int i = 0; i < 4; ++i)
        a[i] = *reinterpret_cast<const bfrag*>(&As[wm * 64 + i * 16 + fr][(kk * 32 + fq * 8) ^ xsw]);
      #pragma unroll
      for (int j = 0; j < 4; ++j)
        b[j] = *reinterpret_cast<const bfrag*>(&Bs[wn * 64 + j * 16 + fr][(kk * 32 + fq * 8) ^ xsw]);
      #pragma unroll
      for (int i = 0; i < 4; ++i)
        #pragma unroll
        for (int j = 0; j < 4; ++j)
          acc[i][j] = __builtin_amdgcn_mfma_f32_16x16x32_bf16(b[j], a[i], acc[i][j], 0, 0, 0);
    }
  }

  // epilogue: D-row <-> n (4 consecutive per lane), D-col <-> m. 8B stores.
  unsigned short* outb = (wsel == 0) ? qb : (wsel == 1) ? kb : vb;
  // fold 1/sqrt(64) AND log2(e) into q so attention scores are in exp2 domain
  const float qscale = (wsel == 0) ? 0.125f * 1.44269504088896f : 1.0f;
  const int b_ = m0 >> 12;
  #pragma unroll
  for (int j = 0; j < 4; ++j) {
    int nl = nloc0 + wn * 64 + j * 16 + fq * 4;        // 4 consecutive n
    int h = nl >> 6, d0 = nl & 63;
    float4 bs4 = *reinterpret_cast<const float4*>(&bias[nl]);
    unsigned short* obase = outb + (size_t)(b_ * NH + h) * SQ * DH + d0;
    #pragma unroll
    for (int i = 0; i < 4; ++i) {
      int m = m0 + wm * 64 + i * 16 + fr;              // D-col = lane&15
      int srow_ = m & (SQ - 1);
      f32x4 v = acc[i][j];
      uint2 pk;
      pk.x = f2bf2((v[0] + bs4.x) * qscale, (v[1] + bs4.y) * qscale);
      pk.y = f2bf2((v[2] + bs4.z) * qscale, (v[3] + bs4.w) * qscale);
      *reinterpret_cast<uint2*>(&obase[(size_t)srow_ * DH]) = pk;
    }
  }
}

// ---------------- kernel 2: sliding-window flash attention (32x32 MFMA) ----------------
// 1D grid 1536, XCD-bijective swizzle (each XCD: 6 heads' K/V ~ L2-resident;
// adjacent chunks share 2/3 of key window). 4 waves x 32 queries; swapped QK^T;
// online softmax (defer-max, exp2); P->A-frag via cvt_pk + shfl_xor(32); K prefetch.
#define VLD 392          // 384 keys + 8 pad (stride 196 dwords -> b128 at conflict floor)
#define THR 11.6f        // defer-max threshold (8 nats in log2 units)

__global__ __launch_bounds__(256, 3) void attn_kernel(
    const unsigned short* __restrict__ qb,
    const unsigned short* __restrict__ kb,
    const unsigned short* __restrict__ vb,
    float* __restrict__ out)
{
  __shared__ unsigned short Vt[DH][VLD];     // V^T for this block's 384-key range

  const int id = blockIdx.x;                 // 1536 blocks, 1536%8==0
  const int swz = (id & 7) * (BH * SQ / 128 / 8) + (id >> 3);
  const int c = swz & 31;                    // query chunk (fast within XCD range)
  const int bh = swz >> 5;                   // head
  const int t = threadIdx.x;
  const int lane = t & 63;
  const int w = t >> 6;
  const int b_ = bh / NH, hd = bh - b_ * NH;
  const int qi = lane & 31, h = lane >> 5;

  const unsigned short* Qbh = qb + bh * (SQ * DH);
  const unsigned short* Kbh = kb + bh * (SQ * DH);
  const unsigned short* Vbh = vb + bh * (SQ * DH);

  const int kstart = c * 128 - WIN;          // block key range [kstart, kstart+384)

  // ---- stage V^T: item = (kg 0..47 [8 keys], dg 0..15 [4 d]); 16B LDS writes ----
  for (int it = t; it < 48 * 16; it += 256) {
    int dg = it & 15, kg = it >> 4;
    int kr = kstart + kg * 8;
    ushort4 va[8];
    #pragma unroll
    for (int rr = 0; rr < 8; ++rr) {
      int k = kr + rr;
      int kc = k < 0 ? 0 : (k > SQ - 1 ? SQ - 1 : k);
      va[rr] = *reinterpret_cast<const ushort4*>(&Vbh[(size_t)kc * DH + dg * 4]);
    }
    #pragma unroll
    for (int j = 0; j < 4; ++j) {
      us8 row;
      #pragma unroll
      for (int i = 0; i < 8; ++i)
        row[i] = reinterpret_cast<const unsigned short*>(&va[i])[j];
      *reinterpret_cast<us8*>(&Vt[dg * 4 + j][kg * 8]) = row;
    }
  }
  __syncthreads();

  // ---- per-wave setup ----
  const int q0w = c * 128 + w * 32;
  const int q = q0w + qi;
  const int kw = q0w - WIN;
  bfrag qf[4];
  #pragma unroll
  for (int kk = 0; kk < 4; ++kk)
    qf[kk] = *reinterpret_cast<const bfrag*>(&Qbh[(size_t)q * DH + kk * 16 + h * 8]);

  const int lo = (-q > -WIN) ? -q : -WIN;
  const int hi = (SQ - 1 - q < WIN) ? (SQ - 1 - q) : WIN;
  const int hq = 4 * h - qi;
  const bool edge = (c == 0) || (c == 31);

  f32x16 c0 = {}, c1 = {};
  float m = -3e38f, ls = 0.f;

  // prefetch K tile 0
  bfrag kf[4];
  {
    int krow = kw + qi;
    int kc = krow < 0 ? 0 : (krow > SQ - 1 ? SQ - 1 : krow);
    #pragma unroll
    for (int kk = 0; kk < 4; ++kk)
      kf[kk] = *reinterpret_cast<const bfrag*>(&Kbh[(size_t)kc * DH + kk * 16 + h * 8]);
  }

  for (int kt = 0; kt < 9; ++kt) {
    // issue K loads for tile kt+1 (overlaps with this tile's compute)
    bfrag kfn[4];
    if (kt < 8) {
      int krow = kw + (kt + 1) * 32 + qi;
      int kc = krow < 0 ? 0 : (krow > SQ - 1 ? SQ - 1 : krow);
      #pragma unroll
      for (int kk = 0; kk < 4; ++kk)
        kfn[kk] = *reinterpret_cast<const bfrag*>(&Kbh[(size_t)kc * DH + kk * 16 + h * 8]);
    }

    f32x16 D = {};
    __builtin_amdgcn_s_setprio(1);
    #pragma unroll
    for (int kk = 0; kk < 4; ++kk)
      D = __builtin_amdgcn_mfma_f32_32x32x16_bf16(kf[kk], qf[kk], D, 0, 0, 0);
    __builtin_amdgcn_s_setprio(0);

    // mask (only boundary tiles / edge blocks need it)
    if (edge || kt == 0 || kt == 8) {
      #pragma unroll
      for (int r = 0; r < 16; ++r) {
        int klocal = (r & 3) + 8 * (r >> 2);
        int dk = kt * 32 + klocal - WIN + hq;
        if (dk < lo || dk > hi) D[r] = -1e30f;
      }
    }

    // tile max (per q column)
    float pm = D[0];
    #pragma unroll
    for (int r = 1; r < 16; ++r) pm = fmaxf(pm, D[r]);
    pm = fmaxf(pm, __shfl_xor(pm, 32));

    // defer-max online rescale
    if (!__all(pm <= m + THR)) {
      float mn = fmaxf(m, pm);
      float al = __builtin_amdgcn_exp2f(m - mn);
      #pragma unroll
      for (int r = 0; r < 16; ++r) {
        float av = __shfl(al, (r & 3) + 8 * (r >> 2) + 4 * h);
        c0[r] *= av; c1[r] *= av;
      }
      ls *= al;
      m = mn;
    }

    // P = exp2(D - m); row-sum partials
    float p[16];
    float sum = 0.f;
    #pragma unroll
    for (int r = 0; r < 16; ++r) {
      p[r] = __builtin_amdgcn_exp2f(D[r] - m);
      sum += p[r];
    }
    ls += sum;

    // convert to bf16 pairs, exchange halves -> PV A-frags
    unsigned U[8];
    #pragma unroll
    for (int g = 0; g < 8; ++g) U[g] = cvtpk(p[2 * g], p[2 * g + 1]);

    unsigned f0[4], f1[4];
    {
      unsigned x, y, xs, ys;
      x = U[0]; y = U[2]; xs = __shfl_xor(x, 32); ys = __shfl_xor(y, 32);
      f0[0] = h ? ys : x;  f0[2] = h ? y : xs;
      x = U[1]; y = U[3]; xs = __shfl_xor(x, 32); ys = __shfl_xor(y, 32);
      f0[1] = h ? ys : x;  f0[3] = h ? y : xs;
      x = U[4]; y = U[6]; xs = __shfl_xor(x, 32); ys = __shfl_xor(y, 32);
      f1[0] = h ? ys : x;  f1[2] = h ? y : xs;
      x = U[5]; y = U[7]; xs = __shfl_xor(x, 32); ys = __shfl_xor(y, 32);
      f1[1] = h ? ys : x;  f1[3] = h ? y : xs;
    }

    // PV: 2 k-steps x 2 d-tiles
    const int colbase = w * 32 + kt * 32;
    bfrag paA, paB;
    {
      uint4 ua = {f0[0], f0[1], f0[2], f0[3]};
      uint4 ub = {f1[0], f1[1], f1[2], f1[3]};
      paA = *reinterpret_cast<bfrag*>(&ua);
      paB = *reinterpret_cast<bfrag*>(&ub);
    }
    bfrag v00 = *reinterpret_cast<const bfrag*>(&Vt[qi][colbase + h * 8]);
    bfrag v01 = *reinterpret_cast<const bfrag*>(&Vt[32 + qi][colbase + h * 8]);
    bfrag v10 = *reinterpret_cast<const bfrag*>(&Vt[qi][colbase + 16 + h * 8]);
    bfrag v11 = *reinterpret_cast<const bfrag*>(&Vt[32 + qi][colbase + 16 + h * 8]);
    __builtin_amdgcn_s_setprio(1);
    c0 = __builtin_amdgcn_mfma_f32_32x32x16_bf16(paA, v00, c0, 0, 0, 0);
    c1 = __builtin_amdgcn_mfma_f32_32x32x16_bf16(paA, v01, c1, 0, 0, 0);
    c0 = __builtin_amdgcn_mfma_f32_32x32x16_bf16(paB, v10, c0, 0, 0, 0);
    c1 = __builtin_amdgcn_mfma_f32_32x32x16_bf16(paB, v11, c1, 0, 0, 0);
    __builtin_amdgcn_s_setprio(0);

    #pragma unroll
    for (int kk = 0; kk < 4; ++kk) kf[kk] = kfn[kk];
  }

  // ---- epilogue: combine l across halves, normalize, write ----
  float lt = ls + __shfl_xor(ls, 32);
  float rinv = 1.0f / lt;
  #pragma unroll
  for (int r = 0; r < 16; ++r) {
    int qrow = (r & 3) + 8 * (r >> 2) + 4 * h;
    float rv = __shfl(rinv, qrow);
    size_t obase = (size_t)(b_ * SQ + q0w + qrow) * HIDN + hd * DH;
    out[obase + qi] = c0[r] * rv;
    out[obase + 32 + qi] = c1[r] * rv;
  }
}

extern "C" void kernel_launch(void* const* d_in, const int* in_sizes, int n_in,
                              void* d_out, int out_size, void* d_ws, size_t ws_size,
                              hipStream_t stream) {
  const float* hid = (const float*)d_in[0];
  const float* Wq  = (const float*)d_in[1];
  const float* bq  = (const float*)d_in[2];
  const float* Wk  = (const float*)d_in[3];
  const float* bk  = (const float*)d_in[4];
  const float* Wv  = (const float*)d_in[5];
  const float* bv  = (const float*)d_in[6];
  float* out = (float*)d_out;

  // ws layout: qb | kb | vb (bf16 [48][4096][64] each) | wb bf16 [2304][768] | hb bf16 [16384][768]
  unsigned short* qb = (unsigned short*)d_ws;
  unsigned short* kb = qb + BHD_ELEMS;
  unsigned short* vb = kb + BHD_ELEMS;
  unsigned short* wb = vb + BHD_ELEMS;
  unsigned short* hb = wb + NCOLS * KDIM;

  conv_kernel<<<dim3(WBLK + HBLK), dim3(256), 0, stream>>>(hid, Wq, Wk, Wv, wb, hb);

  dim3 g1(NCOLS * MROWS / (BM * BN));   // 2304, XCD-swizzled in-kernel
  proj_kernel<<<g1, dim3(256), 0, stream>>>(hb, wb, bq, bk, bv, qb, kb, vb);

  dim3 g2(BH * SQ / 128);               // 1536, XCD-swizzled in-kernel
  attn_kernel<<<g2, dim3(256), 0, stream>>>(qb, kb, vb, out);
}